// Round 1
// 300.572 us; speedup vs baseline: 1.0051x; 1.0051x over previous
//
#include <hip/hip_runtime.h>
#include <hip/hip_bf16.h>
#include <stdint.h>

// ---------------------------------------------------------------------------
// JointEmbeddingClassifier on MI355X (gfx950) — R5.
// R4 post-mortem: gemm1 = 77us = 892 TF = the m97-structure ceiling
// (MfmaUtil 37%, bank conflicts 0, HBM 22% -> the syncthreads vmcnt(0) drain
// is the stall). R5 rewrites gemm1 as a counted-vmcnt ring pipeline
// (T3+T4+T5): 256x128 tile (grid 16x16 = 256 blocks = 1/CU, 8 waves),
// K chunked by 32 into a 4-slot LDS ring per operand (96 KB).
// Invariants (per-thread issue stream = 3 gloads/chunk, order A,A,B):
//   - chunk c computes slot c&3, stages chunk c+3 into slot (c-1)&3 whose
//     readers finished before the end-of-(c-1) barrier  -> WAR-safe.
//   - end-of-chunk s_waitcnt vmcnt(6) leaves only chunks {c-1,c}'s 6 loads
//     in flight -> chunk c+1's slots complete before the barrier -> RAW-safe,
//     and loads NEVER drain across a barrier (the m97 stall is gone).
//   - raw s_barrier sandwiched in asm memory fences; lgkm ordering of frag
//     reads is compiler-tracked (no inline-asm ds_read -> rule #18 n/a).
// k_prep / k_head byte-identical to R4 to isolate the variable.
// ---------------------------------------------------------------------------

typedef __attribute__((ext_vector_type(4))) float  floatx4;
typedef __attribute__((ext_vector_type(8))) short  shortx8;
typedef __attribute__((ext_vector_type(4))) short  shortx4;
typedef __attribute__((ext_vector_type(8))) __bf16 bf16x8;

static __device__ __forceinline__ ushort f32_to_bf16_rne(float f) {
  uint32_t u = __builtin_bit_cast(uint32_t, f);
  u += 0x7FFFu + ((u >> 16) & 1u);      // RNE (no NaN inputs here)
  return (ushort)(u >> 16);
}

// async global->LDS, 16B per lane. LDS dest = wave-uniform base + lane*16;
// global address may be fully per-lane (used for perm-indirected rows).
static __device__ __forceinline__ void async_copy16(const void* g, void* lds) {
  __builtin_amdgcn_global_load_lds(
      (__attribute__((address_space(1))) void*)(uintptr_t)g,
      (__attribute__((address_space(3))) void*)(uintptr_t)lds,
      16, 0, 0);
}

// ======================= fused prep (one launch) ===========================
// blocks [0]            : counting sort of y -> perm, offs
// blocks [1, 4224]      : pack cwb [32][128][1024] + Wcb [128][1024]
// blocks [4225, 6272]   : transpose Wp|Ws -> Bt1 bf16 [2048][4096]
// blocks [6273, 14464]  : cast x f32 -> bf16
__global__ __launch_bounds__(256) void k_prep(
    const float* __restrict__ x,   const int* __restrict__ y,
    const float* __restrict__ Wp,  const float* __restrict__ Ws,
    const float* __restrict__ Wc,
    const float* __restrict__ cw0, const float* __restrict__ cw1,
    ushort* __restrict__ xb,  ushort* __restrict__ Bt1,
    ushort* __restrict__ cwb, ushort* __restrict__ Wcb,
    int* __restrict__ perm, int* __restrict__ offs)
{
  __shared__ __align__(16) ushort tile[64 * 72];
  __shared__ int hist[32], hbase[32], hcur[32];
  const int b = blockIdx.x;
  const int t = threadIdx.x;

  if (b == 0) {
    // ---- bucket: counting sort by class (intra-class order irrelevant) ----
    if (t < 32) { hist[t] = 0; hcur[t] = 0; }
    __syncthreads();
    int yv[16];
    #pragma unroll
    for (int i = 0; i < 16; ++i) { yv[i] = y[t * 16 + i]; atomicAdd(&hist[yv[i]], 1); }
    __syncthreads();
    if (t == 0) {
      int s = 0;
      for (int c = 0; c < 32; ++c) { hbase[c] = s; offs[c] = s; s += hist[c]; }
      offs[32] = s;
    }
    __syncthreads();
    #pragma unroll
    for (int i = 0; i < 16; ++i) {
      const int c = yv[i];
      const int p = atomicAdd(&hcur[c], 1);
      perm[hbase[c] + p] = t * 16 + i;
    }
  } else if (b <= 4224) {
    // ---- pack cwb (rows: 32 cw0 | 64 cw1 | 32 zero per class) + Wcb ----
    const int row = b - 1;               // 0..4223
    const int k = t * 4;
    float v0 = 0.f, v1 = 0.f, v2 = 0.f, v3 = 0.f;
    ushort* dst;
    if (row < 4096) {
      const int c = row >> 7, n = row & 127;
      if (n < 32) {
        floatx4 f = *reinterpret_cast<const floatx4*>(cw0 + (size_t)(c * 32 + n) * 1024 + k);
        v0 = f[0]; v1 = f[1]; v2 = f[2]; v3 = f[3];
      } else if (n < 96) {
        floatx4 f = *reinterpret_cast<const floatx4*>(cw1 + (size_t)(c * 64 + (n - 32)) * 1024 + k);
        v0 = f[0]; v1 = f[1]; v2 = f[2]; v3 = f[3];
      }
      dst = cwb + (size_t)row * 1024 + k;
    } else {
      const int n = row - 4096;          // 0..127
      if (n < 32) {
        v0 = Wc[(k + 0) * 32 + n]; v1 = Wc[(k + 1) * 32 + n];
        v2 = Wc[(k + 2) * 32 + n]; v3 = Wc[(k + 3) * 32 + n];
      }
      dst = Wcb + (size_t)n * 1024 + k;
    }
    shortx4 o;
    o[0] = (short)f32_to_bf16_rne(v0); o[1] = (short)f32_to_bf16_rne(v1);
    o[2] = (short)f32_to_bf16_rne(v2); o[3] = (short)f32_to_bf16_rne(v3);
    *reinterpret_cast<shortx4*>(dst) = o;
  } else if (b <= 6272) {
    // ---- transpose one 64x64 tile of Wp|Ws into Bt1 (K-contiguous) ----
    const int vt = b - 4225;             // 0..2047
    const int z = vt >> 10, rest = vt & 1023;
    const int nt = rest >> 6, kt = rest & 63;
    const float* W = z ? Ws : Wp;
    const int r = t >> 4, c = (t & 15) * 4;
    #pragma unroll
    for (int j = 0; j < 4; ++j) {
      const int kk = r + j * 16;
      floatx4 v = *reinterpret_cast<const floatx4*>(
          W + (size_t)(kt * 64 + kk) * 1024 + nt * 64 + c);
      tile[(c + 0) * 72 + kk] = f32_to_bf16_rne(v[0]);
      tile[(c + 1) * 72 + kk] = f32_to_bf16_rne(v[1]);
      tile[(c + 2) * 72 + kk] = f32_to_bf16_rne(v[2]);
      tile[(c + 3) * 72 + kk] = f32_to_bf16_rne(v[3]);
    }
    __syncthreads();
    const int nl = t >> 3, ch = t & 7;
    #pragma unroll
    for (int j = 0; j < 2; ++j) {
      const int n = nl + j * 32;
      shortx8 v = *reinterpret_cast<const shortx8*>(tile + n * 72 + ch * 8);
      *reinterpret_cast<shortx8*>(
          Bt1 + (size_t)(z * 1024 + nt * 64 + n) * 4096 + kt * 64 + ch * 8) = v;
    }
  } else {
    // ---- cast x -> bf16 ----
    const size_t i = ((size_t)(b - 6273) * 256 + t) * 8;
    floatx4 a = *reinterpret_cast<const floatx4*>(x + i);
    floatx4 c = *reinterpret_cast<const floatx4*>(x + i + 4);
    shortx8 o;
    o[0] = (short)f32_to_bf16_rne(a[0]); o[1] = (short)f32_to_bf16_rne(a[1]);
    o[2] = (short)f32_to_bf16_rne(a[2]); o[3] = (short)f32_to_bf16_rne(a[3]);
    o[4] = (short)f32_to_bf16_rne(c[0]); o[5] = (short)f32_to_bf16_rne(c[1]);
    o[6] = (short)f32_to_bf16_rne(c[2]); o[7] = (short)f32_to_bf16_rne(c[3]);
    *reinterpret_cast<shortx8*>(xb + i) = o;
  }
}

// ======================= gemm1: 256x128, ring-4 counted-vmcnt pipeline =====
// C[4096,2048] = xb . Bt1^T ; cols 0..1023 -> P (+bp), 1024..2047 -> S (+bs).
// 512 thr = 8 waves (4M x 2N), per-wave 64x64. K chunk = 32 (one MFMA-K).
// LDS: A ring 4 x [256][32] bf16 (64 KB) + B ring 4 x [128][32] (32 KB).
// Swizzle: LDS[row][phys p] = global[row][p ^ (row&3)] (16B chunks), applied
// on the per-lane GLOBAL source (linear LDS dest, m173 pattern) and undone
// on the ds_read side -> <=2-way bank aliasing (free, m136).
__global__ __launch_bounds__(512, 2) void k_gemm1(
    const ushort* __restrict__ xb, const ushort* __restrict__ Bt1,
    const float* __restrict__ bp, const float* __restrict__ bs,
    float* __restrict__ outP, float* __restrict__ outS,
    ushort* __restrict__ Pb, ushort* __restrict__ Sb)
{
  __shared__ __align__(16) ushort lA[4 * 256 * 32];   // 64 KB, 4 ring slots
  __shared__ __align__(16) ushort lB[4 * 128 * 32];   // 32 KB, 4 ring slots

  floatx4 acc[4][4];
  const floatx4 z4 = {0.f, 0.f, 0.f, 0.f};
  #pragma unroll
  for (int i = 0; i < 4; ++i)
    #pragma unroll
    for (int j = 0; j < 4; ++j) acc[i][j] = z4;

  const int t    = threadIdx.x;
  const int w    = t >> 6;
  const int lane = t & 63;
  const int wr   = w >> 1;      // 0..3 : M wave
  const int wc   = w & 1;       // 0..1 : N wave
  const int r16  = lane & 15;
  const int qd   = lane >> 4;

  const ushort* Abase = xb  + (size_t)(blockIdx.x * 256) * 4096;
  const ushort* Bbase = Bt1 + (size_t)(blockIdx.y * 128) * 4096;

  // staging per-thread constants: chunk-idx cidx -> row = cidx>>2, phys p =
  // cidx&3, source logical chunk q = p ^ (row&3).
  const int    rA0  = t >> 2;                               // 0..127
  const int    qs   = ((t & 3) ^ (rA0 & 3)) << 3;           // elem offset
  const size_t sA0  = (size_t)rA0 * 4096 + qs;              // A rows 0..127
  const size_t sA1  = (size_t)(128 + rA0) * 4096 + qs;      // A rows 128..255
  const size_t sB   = (size_t)rA0 * 4096 + qs;              // B rows 0..127
  const int    dUni = (t & ~63) * 8;   // wave-uniform dest base (ushorts)

  // ds-read per-thread bases (ushort units): lane (qd,r16) of frag f reads
  // LDS row = F + r16, phys chunk = qd ^ (r16&3)  (F multiple of 16).
  const int px  = qd ^ (r16 & 3);
  const int aRd = (wr * 64 + r16) * 32 + px * 8;
  const int bRd = (wc * 64 + r16) * 32 + px * 8;

  // ---- prologue: stage chunks 0,1,2 (9 loads; order A,A,B per chunk) ----
  #pragma unroll
  for (int c = 0; c < 3; ++c) {
    const int k0 = c * 32;
    async_copy16(Abase + sA0 + k0, lA + c * 8192 + dUni);
    async_copy16(Abase + sA1 + k0, lA + c * 8192 + 4096 + dUni);
    async_copy16(Bbase + sB  + k0, lB + c * 4096 + dUni);
  }
  asm volatile("s_waitcnt vmcnt(6)" ::: "memory");   // chunk 0 (first 3) done
  __builtin_amdgcn_s_barrier();
  asm volatile("" ::: "memory");

  for (int c = 0; c < 128; ++c) {
    const int slot = c & 3;
    const ushort* As = lA + slot * 8192;
    const ushort* Bs = lB + slot * 4096;

    bf16x8 af[4], bfv[4];
    #pragma unroll
    for (int mi = 0; mi < 4; ++mi)
      af[mi] = *reinterpret_cast<const bf16x8*>(As + aRd + mi * 512);
    #pragma unroll
    for (int ni = 0; ni < 4; ++ni)
      bfv[ni] = *reinterpret_cast<const bf16x8*>(Bs + bRd + ni * 512);

    // stage chunk c+3 into slot (c+3)&3 (= slot of chunk c-1; its readers
    // finished before the end-of-(c-1) barrier). Tail: clamp K offset so the
    // per-chunk issue count stays uniform (3) and vmcnt(6) math holds.
    {
      const int cs  = c + 3;
      const int ss  = cs & 3;
      const int k0s = (cs < 128 ? cs : 127) * 32;
      async_copy16(Abase + sA0 + k0s, lA + ss * 8192 + dUni);
      async_copy16(Abase + sA1 + k0s, lA + ss * 8192 + 4096 + dUni);
      async_copy16(Bbase + sB  + k0s, lB + ss * 4096 + dUni);
    }

    __builtin_amdgcn_s_setprio(1);
    #pragma unroll
    for (int mi = 0; mi < 4; ++mi)
      #pragma unroll
      for (int ni = 0; ni < 4; ++ni)
        acc[mi][ni] = __builtin_amdgcn_mfma_f32_16x16x32_bf16(
            af[mi], bfv[ni], acc[mi][ni], 0, 0, 0);
    __builtin_amdgcn_s_setprio(0);

    // end-of-chunk: <=6 outstanding leaves only chunks {c-1,c}'s loads in
    // flight -> chunk c+1's slots complete. Loads never drain to 0.
    asm volatile("s_waitcnt vmcnt(6)" ::: "memory");
    __builtin_amdgcn_s_barrier();
    asm volatile("" ::: "memory");
  }

  const int sel = (blockIdx.y >= 8);
  const float* bias = sel ? bs : bp;
  float*  outF = sel ? outS : outP;
  ushort* outB = sel ? Sb : Pb;
  const int colbase = blockIdx.y * 128 - sel * 1024;
  #pragma unroll
  for (int mi = 0; mi < 4; ++mi) {
    #pragma unroll
    for (int ni = 0; ni < 4; ++ni) {
      const int n = colbase + wc * 64 + ni * 16 + r16;
      const float bv = bias[n];
      #pragma unroll
      for (int rg = 0; rg < 4; ++rg) {
        const int m = blockIdx.x * 256 + wr * 64 + mi * 16 + qd * 4 + rg;
        const float v = acc[mi][ni][rg] + bv;
        const size_t off = (size_t)m * 1024 + n;
        outF[off] = v;
        outB[off] = f32_to_bf16_rne(v);
      }
    }
  }
}

// ======================= head (BK=64, as R2) ===============================
static __device__ __forceinline__ void mfma_bk_step64(
    const ushort* lA, const ushort* lB, floatx4 acc[4][4],
    int wr, int wc, int r16, int quad)
{
  #pragma unroll
  for (int ks = 0; ks < 2; ++ks) {
    bf16x8 af[4], bfv[4];
    const int pc = (((ks * 4) + quad) ^ (r16 & 7)) * 8;
    #pragma unroll
    for (int mi = 0; mi < 4; ++mi)
      af[mi] = *reinterpret_cast<const bf16x8*>(lA + (wr * 64 + mi * 16 + r16) * 64 + pc);
    #pragma unroll
    for (int ni = 0; ni < 4; ++ni)
      bfv[ni] = *reinterpret_cast<const bf16x8*>(lB + (wc * 64 + ni * 16 + r16) * 64 + pc);
    #pragma unroll
    for (int mi = 0; mi < 4; ++mi)
      #pragma unroll
      for (int ni = 0; ni < 4; ++ni)
        acc[mi][ni] = __builtin_amdgcn_mfma_f32_16x16x32_bf16(
            af[mi], bfv[ni], acc[mi][ni], 0, 0, 0);
  }
}

// blockIdx.y==32: parent logits (A=Pb, B=Wcb). blockIdx.y==c<32: child logits
// for class c — A rows gathered via perm, B=cwb[c]; cols 0..31->child0,
// 32..95->child1.
__global__ __launch_bounds__(256) void k_head(
    const ushort* __restrict__ Sb, const ushort* __restrict__ Pb,
    const ushort* __restrict__ cwb, const ushort* __restrict__ Wcb,
    const int* __restrict__ perm, const int* __restrict__ off,
    const float* __restrict__ cb0, const float* __restrict__ cb1,
    const float* __restrict__ bc,
    float* __restrict__ out0, float* __restrict__ out1,
    float* __restrict__ outParent)
{
  __shared__ __align__(16) ushort lA[128 * 64];
  __shared__ __align__(16) ushort lB[128 * 64];
  floatx4 acc[4][4];
  const floatx4 z4 = {0.f, 0.f, 0.f, 0.f};
  #pragma unroll
  for (int i = 0; i < 4; ++i)
    #pragma unroll
    for (int j = 0; j < 4; ++j) acc[i][j] = z4;

  const int t = threadIdx.x, w = t >> 6, lane = t & 63;
  const int wr = w >> 1, wc = w & 1, r16 = lane & 15, quad = lane >> 4;
  const int sr = lane >> 3, sc = lane & 7;

  if (blockIdx.y == 32) {                       // ---- parent logits ----
    const ushort* Abase = Pb + (size_t)(blockIdx.x * 128) * 1024;
    for (int k0 = 0; k0 < 1024; k0 += 64) {
      #pragma unroll
      for (int c2 = 0; c2 < 4; ++c2) {
        const int r  = 32 * w + 8 * c2 + sr;
        const int gc = sc ^ sr;
        async_copy16(Abase + (size_t)r * 1024 + k0 + gc * 8, lA + (32 * w + 8 * c2) * 64);
        async_copy16(Wcb   + (size_t)r * 1024 + k0 + gc * 8, lB + (32 * w + 8 * c2) * 64);
      }
      __syncthreads();
      mfma_bk_step64(lA, lB, acc, wr, wc, r16, quad);
      __syncthreads();
    }
    if (wc == 0) {
      #pragma unroll
      for (int mi = 0; mi < 4; ++mi)
        #pragma unroll
        for (int ni = 0; ni < 2; ++ni) {
          const int n = ni * 16 + r16;
          const float bv = bc[n];
          #pragma unroll
          for (int rg = 0; rg < 4; ++rg) {
            const int m = blockIdx.x * 128 + wr * 64 + mi * 16 + quad * 4 + rg;
            outParent[(size_t)m * 32 + n] = acc[mi][ni][rg] + bv;
          }
        }
    }
    return;
  }

  // ---- child logits for class c ----
  const int c    = blockIdx.y;
  const int off0 = off[c];
  const int cnt  = off[c + 1] - off0;
  const int m0   = blockIdx.x * 128;
  if (m0 >= cnt) return;                        // block-uniform exit

  int rowSamp[4];
  #pragma unroll
  for (int c2 = 0; c2 < 4; ++c2) {
    const int r = 32 * w + 8 * c2 + sr;
    rowSamp[c2] = perm[off0 + min(m0 + r, cnt - 1)];
  }
  const ushort* Bbase = cwb + (size_t)c * 128 * 1024;

  for (int k0 = 0; k0 < 1024; k0 += 64) {
    #pragma unroll
    for (int c2 = 0; c2 < 4; ++c2) {
      const int r  = 32 * w + 8 * c2 + sr;
      const int gc = sc ^ sr;
      async_copy16(Sb + (size_t)rowSamp[c2] * 1024 + k0 + gc * 8, lA + (32 * w + 8 * c2) * 64);
      async_copy16(Bbase + (size_t)r * 1024 + k0 + gc * 8,        lB + (32 * w + 8 * c2) * 64);
    }
    __syncthreads();
    mfma_bk_step64(lA, lB, acc, wr, wc, r16, quad);
    __syncthreads();
  }

  #pragma unroll
  for (int mi = 0; mi < 4; ++mi) {
    #pragma unroll
    for (int rg = 0; rg < 4; ++rg) {
      const int gm = m0 + wr * 64 + mi * 16 + quad * 4 + rg;
      if (gm >= cnt) continue;
      const int sample = perm[off0 + gm];
      #pragma unroll
      for (int ni = 0; ni < 4; ++ni) {
        const int n = wc * 64 + ni * 16 + r16;
        if (n < 32)
          out0[(size_t)sample * 32 + n] = acc[mi][ni][rg] + cb0[c * 32 + n];
        else if (n < 96)
          out1[(size_t)sample * 64 + (n - 32)] = acc[mi][ni][rg] + cb1[c * 64 + (n - 32)];
      }
    }
  }
}

// ---------------------------------------------------------------------------

extern "C" void kernel_launch(void* const* d_in, const int* in_sizes, int n_in,
                              void* d_out, int out_size, void* d_ws, size_t ws_size,
                              hipStream_t stream) {
  const float* x   = (const float*)d_in[0];
  const int*   y   = (const int*)  d_in[1];
  const float* Wp  = (const float*)d_in[2];
  const float* bp  = (const float*)d_in[3];
  const float* Ws  = (const float*)d_in[4];
  const float* bs  = (const float*)d_in[5];
  const float* Wc  = (const float*)d_in[6];
  const float* bc  = (const float*)d_in[7];
  const float* cw0 = (const float*)d_in[8];
  const float* cb0 = (const float*)d_in[9];
  const float* cw1 = (const float*)d_in[10];
  const float* cb1 = (const float*)d_in[11];

  float* out = (float*)d_out;
  float* parent_logits = out;               // [4096,32]
  float* child0        = out + 131072;      // [4096,32]
  float* child1        = out + 262144;      // [4096,64]
  float* P             = out + 524288;      // [4096,1024]
  float* S             = out + 4718592;     // [4096,1024]

  char* ws = (char*)d_ws;
  ushort* xb   = (ushort*)(ws);                  // 32 MB   [4096][4096]
  ushort* Bt1  = (ushort*)(ws + 33554432);       // 16 MB   [2048][4096]
  ushort* Pb   = (ushort*)(ws + 50331648);       // 8 MB    [4096][1024]
  ushort* Sb   = (ushort*)(ws + 58720256);       // 8 MB    [4096][1024]
  ushort* cwb  = (ushort*)(ws + 67108864);       // 8 MB    [32][128][1024]
  ushort* Wcb  = (ushort*)(ws + 75497472);       // 256 KB  [128][1024]
  int*    perm = (int*)   (ws + 75759616);       // 16 KB
  int*    offs = (int*)   (ws + 75776000);       // 132 B

  k_prep <<<14465, 256, 0, stream>>>(x, y, Wp, Ws, Wc, cw0, cw1,
                                     xb, Bt1, cwb, Wcb, perm, offs);
  k_gemm1<<<dim3(16, 16), 512, 0, stream>>>(xb, Bt1, bp, bs, P, S, Pb, Sb);
  k_head <<<dim3(32, 33), 256, 0, stream>>>(Sb, Pb, cwb, Wcb, perm, offs,
                                            cb0, cb1, bc,
                                            child0, child1, parent_logits);
}

// Round 2
// 294.766 us; speedup vs baseline: 1.0249x; 1.0197x over previous
//
#include <hip/hip_runtime.h>
#include <hip/hip_bf16.h>
#include <stdint.h>

// ---------------------------------------------------------------------------
// JointEmbeddingClassifier on MI355X (gfx950) — R6.
// R5 post-mortem: counted-vmcnt ring worked (VALUBusy 28->18, no drain) but
// BK=32 slots (64B rows, only 4 chunk positions) made every ds_read_b128 a
// 2-way bank conflict: SQ_LDS_BANK_CONFLICT = 8.39M = exactly +4 cy per
// fragment read -> LDS path (the true bottleneck: ~690cy/chunk vs MFMA
// 620cy/chunk per CU) inflated 1.5x, cancelling the pipeline gain.
// R6: ring slots at BK=64 (128B rows, 8 chunk positions) with the
// px = (ks*4+qd) ^ (r16&7) swizzle — the exact k_head pattern measured at
// ZERO conflicts in R4. Ring-3 (144KB LDS), same pipeline invariants:
//   - 6 loads/chunk/thread (A:4, B:2); stage chunk c+2 into slot (c+2)%3 =
//     slot vacated by chunk c-1 (readers done before end-of-(c-1) barrier).
//   - end-of-chunk s_waitcnt vmcnt(6) leaves only chunk c+2's 6 loads in
//     flight -> chunk c+1 resident before its barrier; never drains to 0.
// k_prep / k_head byte-identical to R4/R5.
// ---------------------------------------------------------------------------

typedef __attribute__((ext_vector_type(4))) float  floatx4;
typedef __attribute__((ext_vector_type(8))) short  shortx8;
typedef __attribute__((ext_vector_type(4))) short  shortx4;
typedef __attribute__((ext_vector_type(8))) __bf16 bf16x8;

static __device__ __forceinline__ ushort f32_to_bf16_rne(float f) {
  uint32_t u = __builtin_bit_cast(uint32_t, f);
  u += 0x7FFFu + ((u >> 16) & 1u);      // RNE (no NaN inputs here)
  return (ushort)(u >> 16);
}

// async global->LDS, 16B per lane. LDS dest = wave-uniform base + lane*16;
// global address may be fully per-lane (used for perm-indirected rows).
static __device__ __forceinline__ void async_copy16(const void* g, void* lds) {
  __builtin_amdgcn_global_load_lds(
      (__attribute__((address_space(1))) void*)(uintptr_t)g,
      (__attribute__((address_space(3))) void*)(uintptr_t)lds,
      16, 0, 0);
}

// ======================= fused prep (one launch) ===========================
// blocks [0]            : counting sort of y -> perm, offs
// blocks [1, 4224]      : pack cwb [32][128][1024] + Wcb [128][1024]
// blocks [4225, 6272]   : transpose Wp|Ws -> Bt1 bf16 [2048][4096]
// blocks [6273, 14464]  : cast x f32 -> bf16
__global__ __launch_bounds__(256) void k_prep(
    const float* __restrict__ x,   const int* __restrict__ y,
    const float* __restrict__ Wp,  const float* __restrict__ Ws,
    const float* __restrict__ Wc,
    const float* __restrict__ cw0, const float* __restrict__ cw1,
    ushort* __restrict__ xb,  ushort* __restrict__ Bt1,
    ushort* __restrict__ cwb, ushort* __restrict__ Wcb,
    int* __restrict__ perm, int* __restrict__ offs)
{
  __shared__ __align__(16) ushort tile[64 * 72];
  __shared__ int hist[32], hbase[32], hcur[32];
  const int b = blockIdx.x;
  const int t = threadIdx.x;

  if (b == 0) {
    // ---- bucket: counting sort by class (intra-class order irrelevant) ----
    if (t < 32) { hist[t] = 0; hcur[t] = 0; }
    __syncthreads();
    int yv[16];
    #pragma unroll
    for (int i = 0; i < 16; ++i) { yv[i] = y[t * 16 + i]; atomicAdd(&hist[yv[i]], 1); }
    __syncthreads();
    if (t == 0) {
      int s = 0;
      for (int c = 0; c < 32; ++c) { hbase[c] = s; offs[c] = s; s += hist[c]; }
      offs[32] = s;
    }
    __syncthreads();
    #pragma unroll
    for (int i = 0; i < 16; ++i) {
      const int c = yv[i];
      const int p = atomicAdd(&hcur[c], 1);
      perm[hbase[c] + p] = t * 16 + i;
    }
  } else if (b <= 4224) {
    // ---- pack cwb (rows: 32 cw0 | 64 cw1 | 32 zero per class) + Wcb ----
    const int row = b - 1;               // 0..4223
    const int k = t * 4;
    float v0 = 0.f, v1 = 0.f, v2 = 0.f, v3 = 0.f;
    ushort* dst;
    if (row < 4096) {
      const int c = row >> 7, n = row & 127;
      if (n < 32) {
        floatx4 f = *reinterpret_cast<const floatx4*>(cw0 + (size_t)(c * 32 + n) * 1024 + k);
        v0 = f[0]; v1 = f[1]; v2 = f[2]; v3 = f[3];
      } else if (n < 96) {
        floatx4 f = *reinterpret_cast<const floatx4*>(cw1 + (size_t)(c * 64 + (n - 32)) * 1024 + k);
        v0 = f[0]; v1 = f[1]; v2 = f[2]; v3 = f[3];
      }
      dst = cwb + (size_t)row * 1024 + k;
    } else {
      const int n = row - 4096;          // 0..127
      if (n < 32) {
        v0 = Wc[(k + 0) * 32 + n]; v1 = Wc[(k + 1) * 32 + n];
        v2 = Wc[(k + 2) * 32 + n]; v3 = Wc[(k + 3) * 32 + n];
      }
      dst = Wcb + (size_t)n * 1024 + k;
    }
    shortx4 o;
    o[0] = (short)f32_to_bf16_rne(v0); o[1] = (short)f32_to_bf16_rne(v1);
    o[2] = (short)f32_to_bf16_rne(v2); o[3] = (short)f32_to_bf16_rne(v3);
    *reinterpret_cast<shortx4*>(dst) = o;
  } else if (b <= 6272) {
    // ---- transpose one 64x64 tile of Wp|Ws into Bt1 (K-contiguous) ----
    const int vt = b - 4225;             // 0..2047
    const int z = vt >> 10, rest = vt & 1023;
    const int nt = rest >> 6, kt = rest & 63;
    const float* W = z ? Ws : Wp;
    const int r = t >> 4, c = (t & 15) * 4;
    #pragma unroll
    for (int j = 0; j < 4; ++j) {
      const int kk = r + j * 16;
      floatx4 v = *reinterpret_cast<const floatx4*>(
          W + (size_t)(kt * 64 + kk) * 1024 + nt * 64 + c);
      tile[(c + 0) * 72 + kk] = f32_to_bf16_rne(v[0]);
      tile[(c + 1) * 72 + kk] = f32_to_bf16_rne(v[1]);
      tile[(c + 2) * 72 + kk] = f32_to_bf16_rne(v[2]);
      tile[(c + 3) * 72 + kk] = f32_to_bf16_rne(v[3]);
    }
    __syncthreads();
    const int nl = t >> 3, ch = t & 7;
    #pragma unroll
    for (int j = 0; j < 2; ++j) {
      const int n = nl + j * 32;
      shortx8 v = *reinterpret_cast<const shortx8*>(tile + n * 72 + ch * 8);
      *reinterpret_cast<shortx8*>(
          Bt1 + (size_t)(z * 1024 + nt * 64 + n) * 4096 + kt * 64 + ch * 8) = v;
    }
  } else {
    // ---- cast x -> bf16 ----
    const size_t i = ((size_t)(b - 6273) * 256 + t) * 8;
    floatx4 a = *reinterpret_cast<const floatx4*>(x + i);
    floatx4 c = *reinterpret_cast<const floatx4*>(x + i + 4);
    shortx8 o;
    o[0] = (short)f32_to_bf16_rne(a[0]); o[1] = (short)f32_to_bf16_rne(a[1]);
    o[2] = (short)f32_to_bf16_rne(a[2]); o[3] = (short)f32_to_bf16_rne(a[3]);
    o[4] = (short)f32_to_bf16_rne(c[0]); o[5] = (short)f32_to_bf16_rne(c[1]);
    o[6] = (short)f32_to_bf16_rne(c[2]); o[7] = (short)f32_to_bf16_rne(c[3]);
    *reinterpret_cast<shortx8*>(xb + i) = o;
  }
}

// ======================= gemm1: 256x128, ring-3 BK=64 counted-vmcnt ========
// C[4096,2048] = xb . Bt1^T ; cols 0..1023 -> P (+bp), 1024..2047 -> S (+bs).
// 512 thr = 8 waves (4M x 2N), per-wave 64x64. K chunk = 64 (two MFMA-K).
// LDS: A ring 3 x [256][64] bf16 (96 KB) + B ring 3 x [128][64] (48 KB).
// Swizzle: LDS[row][phys p] = global[row][p ^ (row&7)] (16B chunks), applied
// on the per-lane GLOBAL source (linear LDS dest, m173) and undone on the
// ds_read side: px = (ks*4+qd) ^ (r16&7) — the k_head pattern, measured
// ZERO conflicts in R4 (8 distinct bank-quads per 8-lane group).
__global__ __launch_bounds__(512, 2) void k_gemm1(
    const ushort* __restrict__ xb, const ushort* __restrict__ Bt1,
    const float* __restrict__ bp, const float* __restrict__ bs,
    float* __restrict__ outP, float* __restrict__ outS,
    ushort* __restrict__ Pb, ushort* __restrict__ Sb)
{
  __shared__ __align__(16) ushort lA[3 * 256 * 64];   // 96 KB, 3 ring slots
  __shared__ __align__(16) ushort lB[3 * 128 * 64];   // 48 KB, 3 ring slots

  floatx4 acc[4][4];
  const floatx4 z4 = {0.f, 0.f, 0.f, 0.f};
  #pragma unroll
  for (int i = 0; i < 4; ++i)
    #pragma unroll
    for (int j = 0; j < 4; ++j) acc[i][j] = z4;

  const int t    = threadIdx.x;
  const int w    = t >> 6;
  const int lane = t & 63;
  const int wr   = w >> 1;      // 0..3 : M wave
  const int wc   = w & 1;       // 0..1 : N wave
  const int r16  = lane & 15;
  const int qd   = lane >> 4;

  const ushort* Abase = xb  + (size_t)(blockIdx.x * 256) * 4096;
  const ushort* Bbase = Bt1 + (size_t)(blockIdx.y * 128) * 4096;

  // staging per-thread constants: per call, thread t covers row = base+(t>>3),
  // physical 16B chunk p = t&7; global source chunk q = p ^ (row&7).
  const int    rS   = t >> 3;                               // 0..63 row-in-call
  const int    qs   = ((t & 7) ^ (rS & 7)) << 3;            // elem offset
  const int    dUni = (t & ~63) * 8;   // wave-uniform dest base (ushorts)

  // ds-read per-thread bases (ushort units): lane (qd,r16) of frag reads
  // LDS row = F + r16 (F multiple of 16), phys chunk = (ks*4+qd) ^ (r16&7).
  const int px0 = (0 * 4 + qd) ^ (r16 & 7);
  const int px1 = (1 * 4 + qd) ^ (r16 & 7);
  const int aRd = (wr * 64 + r16) * 64;
  const int bRd = (wc * 64 + r16) * 64;

  // per-chunk staging: A = 4 calls (64 rows each), B = 2 calls.
  #define STAGE_CHUNK(slot, k0)                                                \
    do {                                                                       \
      _Pragma("unroll")                                                        \
      for (int j = 0; j < 4; ++j)                                              \
        async_copy16(Abase + (size_t)(j * 64 + rS) * 4096 + (k0) + qs,         \
                     lA + (slot) * 16384 + j * 4096 + dUni);                   \
      _Pragma("unroll")                                                        \
      for (int j = 0; j < 2; ++j)                                              \
        async_copy16(Bbase + (size_t)(j * 64 + rS) * 4096 + (k0) + qs,         \
                     lB + (slot) * 8192 + j * 4096 + dUni);                    \
    } while (0)

  // ---- prologue: stage chunks 0,1 (12 loads) ----
  STAGE_CHUNK(0, 0);
  STAGE_CHUNK(1, 64);
  asm volatile("s_waitcnt vmcnt(6)" ::: "memory");   // chunk 0's 6 done
  __builtin_amdgcn_s_barrier();
  asm volatile("" ::: "memory");

  for (int c = 0; c < 64; ++c) {
    const int slot = c % 3;
    const ushort* As = lA + slot * 16384;
    const ushort* Bs = lB + slot * 8192;

    bf16x8 af[2][4], bfv[2][4];
    #pragma unroll
    for (int mi = 0; mi < 4; ++mi) {
      af[0][mi] = *reinterpret_cast<const bf16x8*>(As + aRd + mi * 1024 + px0 * 8);
      af[1][mi] = *reinterpret_cast<const bf16x8*>(As + aRd + mi * 1024 + px1 * 8);
    }
    #pragma unroll
    for (int ni = 0; ni < 4; ++ni) {
      bfv[0][ni] = *reinterpret_cast<const bf16x8*>(Bs + bRd + ni * 1024 + px0 * 8);
      bfv[1][ni] = *reinterpret_cast<const bf16x8*>(Bs + bRd + ni * 1024 + px1 * 8);
    }

    // stage chunk c+2 into slot (c+2)%3 (= slot of chunk c-1; its readers
    // finished before the end-of-(c-1) barrier). Tail: clamp K offset so the
    // per-chunk issue count stays uniform (6) and vmcnt(6) math holds.
    {
      const int cs  = c + 2;
      const int ss  = cs % 3;
      const int k0s = (cs < 64 ? cs : 63) * 64;
      STAGE_CHUNK(ss, k0s);
    }

    __builtin_amdgcn_s_setprio(1);
    #pragma unroll
    for (int ks = 0; ks < 2; ++ks)
      #pragma unroll
      for (int mi = 0; mi < 4; ++mi)
        #pragma unroll
        for (int ni = 0; ni < 4; ++ni)
          acc[mi][ni] = __builtin_amdgcn_mfma_f32_16x16x32_bf16(
              af[ks][mi], bfv[ks][ni], acc[mi][ni], 0, 0, 0);
    __builtin_amdgcn_s_setprio(0);

    // end-of-chunk: <=6 outstanding leaves only chunk c+2's loads in flight
    // -> chunk c+1's slot complete. Loads never drain to 0.
    asm volatile("s_waitcnt vmcnt(6)" ::: "memory");
    __builtin_amdgcn_s_barrier();
    asm volatile("" ::: "memory");
  }
  #undef STAGE_CHUNK

  const int sel = (blockIdx.y >= 8);
  const float* bias = sel ? bs : bp;
  float*  outF = sel ? outS : outP;
  ushort* outB = sel ? Sb : Pb;
  const int colbase = blockIdx.y * 128 - sel * 1024;
  #pragma unroll
  for (int mi = 0; mi < 4; ++mi) {
    #pragma unroll
    for (int ni = 0; ni < 4; ++ni) {
      const int n = colbase + wc * 64 + ni * 16 + r16;
      const float bv = bias[n];
      #pragma unroll
      for (int rg = 0; rg < 4; ++rg) {
        const int m = blockIdx.x * 256 + wr * 64 + mi * 16 + qd * 4 + rg;
        const float v = acc[mi][ni][rg] + bv;
        const size_t off = (size_t)m * 1024 + n;
        outF[off] = v;
        outB[off] = f32_to_bf16_rne(v);
      }
    }
  }
}

// ======================= head (BK=64, as R2) ===============================
static __device__ __forceinline__ void mfma_bk_step64(
    const ushort* lA, const ushort* lB, floatx4 acc[4][4],
    int wr, int wc, int r16, int quad)
{
  #pragma unroll
  for (int ks = 0; ks < 2; ++ks) {
    bf16x8 af[4], bfv[4];
    const int pc = (((ks * 4) + quad) ^ (r16 & 7)) * 8;
    #pragma unroll
    for (int mi = 0; mi < 4; ++mi)
      af[mi] = *reinterpret_cast<const bf16x8*>(lA + (wr * 64 + mi * 16 + r16) * 64 + pc);
    #pragma unroll
    for (int ni = 0; ni < 4; ++ni)
      bfv[ni] = *reinterpret_cast<const bf16x8*>(lB + (wc * 64 + ni * 16 + r16) * 64 + pc);
    #pragma unroll
    for (int mi = 0; mi < 4; ++mi)
      #pragma unroll
      for (int ni = 0; ni < 4; ++ni)
        acc[mi][ni] = __builtin_amdgcn_mfma_f32_16x16x32_bf16(
            af[mi], bfv[ni], acc[mi][ni], 0, 0, 0);
  }
}

// blockIdx.y==32: parent logits (A=Pb, B=Wcb). blockIdx.y==c<32: child logits
// for class c — A rows gathered via perm, B=cwb[c]; cols 0..31->child0,
// 32..95->child1.
__global__ __launch_bounds__(256) void k_head(
    const ushort* __restrict__ Sb, const ushort* __restrict__ Pb,
    const ushort* __restrict__ cwb, const ushort* __restrict__ Wcb,
    const int* __restrict__ perm, const int* __restrict__ off,
    const float* __restrict__ cb0, const float* __restrict__ cb1,
    const float* __restrict__ bc,
    float* __restrict__ out0, float* __restrict__ out1,
    float* __restrict__ outParent)
{
  __shared__ __align__(16) ushort lA[128 * 64];
  __shared__ __align__(16) ushort lB[128 * 64];
  floatx4 acc[4][4];
  const floatx4 z4 = {0.f, 0.f, 0.f, 0.f};
  #pragma unroll
  for (int i = 0; i < 4; ++i)
    #pragma unroll
    for (int j = 0; j < 4; ++j) acc[i][j] = z4;

  const int t = threadIdx.x, w = t >> 6, lane = t & 63;
  const int wr = w >> 1, wc = w & 1, r16 = lane & 15, quad = lane >> 4;
  const int sr = lane >> 3, sc = lane & 7;

  if (blockIdx.y == 32) {                       // ---- parent logits ----
    const ushort* Abase = Pb + (size_t)(blockIdx.x * 128) * 1024;
    for (int k0 = 0; k0 < 1024; k0 += 64) {
      #pragma unroll
      for (int c2 = 0; c2 < 4; ++c2) {
        const int r  = 32 * w + 8 * c2 + sr;
        const int gc = sc ^ sr;
        async_copy16(Abase + (size_t)r * 1024 + k0 + gc * 8, lA + (32 * w + 8 * c2) * 64);
        async_copy16(Wcb   + (size_t)r * 1024 + k0 + gc * 8, lB + (32 * w + 8 * c2) * 64);
      }
      __syncthreads();
      mfma_bk_step64(lA, lB, acc, wr, wc, r16, quad);
      __syncthreads();
    }
    if (wc == 0) {
      #pragma unroll
      for (int mi = 0; mi < 4; ++mi)
        #pragma unroll
        for (int ni = 0; ni < 2; ++ni) {
          const int n = ni * 16 + r16;
          const float bv = bc[n];
          #pragma unroll
          for (int rg = 0; rg < 4; ++rg) {
            const int m = blockIdx.x * 128 + wr * 64 + mi * 16 + quad * 4 + rg;
            outParent[(size_t)m * 32 + n] = acc[mi][ni][rg] + bv;
          }
        }
    }
    return;
  }

  // ---- child logits for class c ----
  const int c    = blockIdx.y;
  const int off0 = off[c];
  const int cnt  = off[c + 1] - off0;
  const int m0   = blockIdx.x * 128;
  if (m0 >= cnt) return;                        // block-uniform exit

  int rowSamp[4];
  #pragma unroll
  for (int c2 = 0; c2 < 4; ++c2) {
    const int r = 32 * w + 8 * c2 + sr;
    rowSamp[c2] = perm[off0 + min(m0 + r, cnt - 1)];
  }
  const ushort* Bbase = cwb + (size_t)c * 128 * 1024;

  for (int k0 = 0; k0 < 1024; k0 += 64) {
    #pragma unroll
    for (int c2 = 0; c2 < 4; ++c2) {
      const int r  = 32 * w + 8 * c2 + sr;
      const int gc = sc ^ sr;
      async_copy16(Sb + (size_t)rowSamp[c2] * 1024 + k0 + gc * 8, lA + (32 * w + 8 * c2) * 64);
      async_copy16(Bbase + (size_t)r * 1024 + k0 + gc * 8,        lB + (32 * w + 8 * c2) * 64);
    }
    __syncthreads();
    mfma_bk_step64(lA, lB, acc, wr, wc, r16, quad);
    __syncthreads();
  }

  #pragma unroll
  for (int mi = 0; mi < 4; ++mi) {
    #pragma unroll
    for (int rg = 0; rg < 4; ++rg) {
      const int gm = m0 + wr * 64 + mi * 16 + quad * 4 + rg;
      if (gm >= cnt) continue;
      const int sample = perm[off0 + gm];
      #pragma unroll
      for (int ni = 0; ni < 4; ++ni) {
        const int n = wc * 64 + ni * 16 + r16;
        if (n < 32)
          out0[(size_t)sample * 32 + n] = acc[mi][ni][rg] + cb0[c * 32 + n];
        else if (n < 96)
          out1[(size_t)sample * 64 + (n - 32)] = acc[mi][ni][rg] + cb1[c * 64 + (n - 32)];
      }
    }
  }
}

// ---------------------------------------------------------------------------

extern "C" void kernel_launch(void* const* d_in, const int* in_sizes, int n_in,
                              void* d_out, int out_size, void* d_ws, size_t ws_size,
                              hipStream_t stream) {
  const float* x   = (const float*)d_in[0];
  const int*   y   = (const int*)  d_in[1];
  const float* Wp  = (const float*)d_in[2];
  const float* bp  = (const float*)d_in[3];
  const float* Ws  = (const float*)d_in[4];
  const float* bs  = (const float*)d_in[5];
  const float* Wc  = (const float*)d_in[6];
  const float* bc  = (const float*)d_in[7];
  const float* cw0 = (const float*)d_in[8];
  const float* cb0 = (const float*)d_in[9];
  const float* cw1 = (const float*)d_in[10];
  const float* cb1 = (const float*)d_in[11];

  float* out = (float*)d_out;
  float* parent_logits = out;               // [4096,32]
  float* child0        = out + 131072;      // [4096,32]
  float* child1        = out + 262144;      // [4096,64]
  float* P             = out + 524288;      // [4096,1024]
  float* S             = out + 4718592;     // [4096,1024]

  char* ws = (char*)d_ws;
  ushort* xb   = (ushort*)(ws);                  // 32 MB   [4096][4096]
  ushort* Bt1  = (ushort*)(ws + 33554432);       // 16 MB   [2048][4096]
  ushort* Pb   = (ushort*)(ws + 50331648);       // 8 MB    [4096][1024]
  ushort* Sb   = (ushort*)(ws + 58720256);       // 8 MB    [4096][1024]
  ushort* cwb  = (ushort*)(ws + 67108864);       // 8 MB    [32][128][1024]
  ushort* Wcb  = (ushort*)(ws + 75497472);       // 256 KB  [128][1024]
  int*    perm = (int*)   (ws + 75759616);       // 16 KB
  int*    offs = (int*)   (ws + 75776000);       // 132 B

  k_prep <<<14465, 256, 0, stream>>>(x, y, Wp, Ws, Wc, cw0, cw1,
                                     xb, Bt1, cwb, Wcb, perm, offs);
  k_gemm1<<<dim3(16, 16), 512, 0, stream>>>(xb, Bt1, bp, bs, P, S, Pb, Sb);
  k_head <<<dim3(32, 33), 256, 0, stream>>>(Sb, Pb, cwb, Wcb, perm, offs,
                                            cb0, cb1, bc,
                                            child0, child1, parent_logits);
}

// Round 3
// 252.505 us; speedup vs baseline: 1.1964x; 1.1674x over previous
//
#include <hip/hip_runtime.h>
#include <hip/hip_bf16.h>
#include <stdint.h>

// ---------------------------------------------------------------------------
// JointEmbeddingClassifier on MI355X (gfx950) — R7.
// R6 post-mortem: gemm1 conflict-fix landed (gemm1 out of top-5, total -6us).
// New bottleneck exposed: k_head = 73.5us at 1% MfmaUtil / 1.5% occupancy /
// 3% HBM — every pipe idle. Cause: live child blocks were (x=0, y=c) ->
// linear ids {0,32,...,992}, all == 0 mod 8 -> ALL on XCD 0 (and 4-deep on
// 8 CUs under %256): 248/256 CUs idle, latency-bound blocks serialized.
// R7: (1) k_head grid transposed to (x=class|parent 33, y=m-tile 32) ->
//     live ids {0..32} u {32+33y} spread across all XCDs under any
//     round-robin; (2) k_head K-loop rewritten as the ring-3 BK=64
//     counted-vmcnt pipeline proven in gemm1 (stage c+2 while computing c,
//     vmcnt(8) = 8 loads/chunk/thread, loads never drain across barriers).
// k_prep / k_gemm1 byte-identical to R6.
// ---------------------------------------------------------------------------

typedef __attribute__((ext_vector_type(4))) float  floatx4;
typedef __attribute__((ext_vector_type(8))) short  shortx8;
typedef __attribute__((ext_vector_type(4))) short  shortx4;
typedef __attribute__((ext_vector_type(8))) __bf16 bf16x8;

static __device__ __forceinline__ ushort f32_to_bf16_rne(float f) {
  uint32_t u = __builtin_bit_cast(uint32_t, f);
  u += 0x7FFFu + ((u >> 16) & 1u);      // RNE (no NaN inputs here)
  return (ushort)(u >> 16);
}

// async global->LDS, 16B per lane. LDS dest = wave-uniform base + lane*16;
// global address may be fully per-lane (used for perm-indirected rows).
static __device__ __forceinline__ void async_copy16(const void* g, void* lds) {
  __builtin_amdgcn_global_load_lds(
      (__attribute__((address_space(1))) void*)(uintptr_t)g,
      (__attribute__((address_space(3))) void*)(uintptr_t)lds,
      16, 0, 0);
}

// ======================= fused prep (one launch) ===========================
// blocks [0]            : counting sort of y -> perm, offs
// blocks [1, 4224]      : pack cwb [32][128][1024] + Wcb [128][1024]
// blocks [4225, 6272]   : transpose Wp|Ws -> Bt1 bf16 [2048][4096]
// blocks [6273, 14464]  : cast x f32 -> bf16
__global__ __launch_bounds__(256) void k_prep(
    const float* __restrict__ x,   const int* __restrict__ y,
    const float* __restrict__ Wp,  const float* __restrict__ Ws,
    const float* __restrict__ Wc,
    const float* __restrict__ cw0, const float* __restrict__ cw1,
    ushort* __restrict__ xb,  ushort* __restrict__ Bt1,
    ushort* __restrict__ cwb, ushort* __restrict__ Wcb,
    int* __restrict__ perm, int* __restrict__ offs)
{
  __shared__ __align__(16) ushort tile[64 * 72];
  __shared__ int hist[32], hbase[32], hcur[32];
  const int b = blockIdx.x;
  const int t = threadIdx.x;

  if (b == 0) {
    // ---- bucket: counting sort by class (intra-class order irrelevant) ----
    if (t < 32) { hist[t] = 0; hcur[t] = 0; }
    __syncthreads();
    int yv[16];
    #pragma unroll
    for (int i = 0; i < 16; ++i) { yv[i] = y[t * 16 + i]; atomicAdd(&hist[yv[i]], 1); }
    __syncthreads();
    if (t == 0) {
      int s = 0;
      for (int c = 0; c < 32; ++c) { hbase[c] = s; offs[c] = s; s += hist[c]; }
      offs[32] = s;
    }
    __syncthreads();
    #pragma unroll
    for (int i = 0; i < 16; ++i) {
      const int c = yv[i];
      const int p = atomicAdd(&hcur[c], 1);
      perm[hbase[c] + p] = t * 16 + i;
    }
  } else if (b <= 4224) {
    // ---- pack cwb (rows: 32 cw0 | 64 cw1 | 32 zero per class) + Wcb ----
    const int row = b - 1;               // 0..4223
    const int k = t * 4;
    float v0 = 0.f, v1 = 0.f, v2 = 0.f, v3 = 0.f;
    ushort* dst;
    if (row < 4096) {
      const int c = row >> 7, n = row & 127;
      if (n < 32) {
        floatx4 f = *reinterpret_cast<const floatx4*>(cw0 + (size_t)(c * 32 + n) * 1024 + k);
        v0 = f[0]; v1 = f[1]; v2 = f[2]; v3 = f[3];
      } else if (n < 96) {
        floatx4 f = *reinterpret_cast<const floatx4*>(cw1 + (size_t)(c * 64 + (n - 32)) * 1024 + k);
        v0 = f[0]; v1 = f[1]; v2 = f[2]; v3 = f[3];
      }
      dst = cwb + (size_t)row * 1024 + k;
    } else {
      const int n = row - 4096;          // 0..127
      if (n < 32) {
        v0 = Wc[(k + 0) * 32 + n]; v1 = Wc[(k + 1) * 32 + n];
        v2 = Wc[(k + 2) * 32 + n]; v3 = Wc[(k + 3) * 32 + n];
      }
      dst = Wcb + (size_t)n * 1024 + k;
    }
    shortx4 o;
    o[0] = (short)f32_to_bf16_rne(v0); o[1] = (short)f32_to_bf16_rne(v1);
    o[2] = (short)f32_to_bf16_rne(v2); o[3] = (short)f32_to_bf16_rne(v3);
    *reinterpret_cast<shortx4*>(dst) = o;
  } else if (b <= 6272) {
    // ---- transpose one 64x64 tile of Wp|Ws into Bt1 (K-contiguous) ----
    const int vt = b - 4225;             // 0..2047
    const int z = vt >> 10, rest = vt & 1023;
    const int nt = rest >> 6, kt = rest & 63;
    const float* W = z ? Ws : Wp;
    const int r = t >> 4, c = (t & 15) * 4;
    #pragma unroll
    for (int j = 0; j < 4; ++j) {
      const int kk = r + j * 16;
      floatx4 v = *reinterpret_cast<const floatx4*>(
          W + (size_t)(kt * 64 + kk) * 1024 + nt * 64 + c);
      tile[(c + 0) * 72 + kk] = f32_to_bf16_rne(v[0]);
      tile[(c + 1) * 72 + kk] = f32_to_bf16_rne(v[1]);
      tile[(c + 2) * 72 + kk] = f32_to_bf16_rne(v[2]);
      tile[(c + 3) * 72 + kk] = f32_to_bf16_rne(v[3]);
    }
    __syncthreads();
    const int nl = t >> 3, ch = t & 7;
    #pragma unroll
    for (int j = 0; j < 2; ++j) {
      const int n = nl + j * 32;
      shortx8 v = *reinterpret_cast<const shortx8*>(tile + n * 72 + ch * 8);
      *reinterpret_cast<shortx8*>(
          Bt1 + (size_t)(z * 1024 + nt * 64 + n) * 4096 + kt * 64 + ch * 8) = v;
    }
  } else {
    // ---- cast x -> bf16 ----
    const size_t i = ((size_t)(b - 6273) * 256 + t) * 8;
    floatx4 a = *reinterpret_cast<const floatx4*>(x + i);
    floatx4 c = *reinterpret_cast<const floatx4*>(x + i + 4);
    shortx8 o;
    o[0] = (short)f32_to_bf16_rne(a[0]); o[1] = (short)f32_to_bf16_rne(a[1]);
    o[2] = (short)f32_to_bf16_rne(a[2]); o[3] = (short)f32_to_bf16_rne(a[3]);
    o[4] = (short)f32_to_bf16_rne(c[0]); o[5] = (short)f32_to_bf16_rne(c[1]);
    o[6] = (short)f32_to_bf16_rne(c[2]); o[7] = (short)f32_to_bf16_rne(c[3]);
    *reinterpret_cast<shortx8*>(xb + i) = o;
  }
}

// ======================= gemm1: 256x128, ring-3 BK=64 counted-vmcnt ========
// (unchanged from R6)
__global__ __launch_bounds__(512, 2) void k_gemm1(
    const ushort* __restrict__ xb, const ushort* __restrict__ Bt1,
    const float* __restrict__ bp, const float* __restrict__ bs,
    float* __restrict__ outP, float* __restrict__ outS,
    ushort* __restrict__ Pb, ushort* __restrict__ Sb)
{
  __shared__ __align__(16) ushort lA[3 * 256 * 64];   // 96 KB, 3 ring slots
  __shared__ __align__(16) ushort lB[3 * 128 * 64];   // 48 KB, 3 ring slots

  floatx4 acc[4][4];
  const floatx4 z4 = {0.f, 0.f, 0.f, 0.f};
  #pragma unroll
  for (int i = 0; i < 4; ++i)
    #pragma unroll
    for (int j = 0; j < 4; ++j) acc[i][j] = z4;

  const int t    = threadIdx.x;
  const int w    = t >> 6;
  const int lane = t & 63;
  const int wr   = w >> 1;      // 0..3 : M wave
  const int wc   = w & 1;       // 0..1 : N wave
  const int r16  = lane & 15;
  const int qd   = lane >> 4;

  const ushort* Abase = xb  + (size_t)(blockIdx.x * 256) * 4096;
  const ushort* Bbase = Bt1 + (size_t)(blockIdx.y * 128) * 4096;

  const int    rS   = t >> 3;                               // 0..63 row-in-call
  const int    qs   = ((t & 7) ^ (rS & 7)) << 3;            // elem offset
  const int    dUni = (t & ~63) * 8;   // wave-uniform dest base (ushorts)

  const int px0 = (0 * 4 + qd) ^ (r16 & 7);
  const int px1 = (1 * 4 + qd) ^ (r16 & 7);
  const int aRd = (wr * 64 + r16) * 64;
  const int bRd = (wc * 64 + r16) * 64;

  #define STAGE_CHUNK(slot, k0)                                                \
    do {                                                                       \
      _Pragma("unroll")                                                        \
      for (int j = 0; j < 4; ++j)                                              \
        async_copy16(Abase + (size_t)(j * 64 + rS) * 4096 + (k0) + qs,         \
                     lA + (slot) * 16384 + j * 4096 + dUni);                   \
      _Pragma("unroll")                                                        \
      for (int j = 0; j < 2; ++j)                                              \
        async_copy16(Bbase + (size_t)(j * 64 + rS) * 4096 + (k0) + qs,         \
                     lB + (slot) * 8192 + j * 4096 + dUni);                    \
    } while (0)

  STAGE_CHUNK(0, 0);
  STAGE_CHUNK(1, 64);
  asm volatile("s_waitcnt vmcnt(6)" ::: "memory");   // chunk 0's 6 done
  __builtin_amdgcn_s_barrier();
  asm volatile("" ::: "memory");

  for (int c = 0; c < 64; ++c) {
    const int slot = c % 3;
    const ushort* As = lA + slot * 16384;
    const ushort* Bs = lB + slot * 8192;

    bf16x8 af[2][4], bfv[2][4];
    #pragma unroll
    for (int mi = 0; mi < 4; ++mi) {
      af[0][mi] = *reinterpret_cast<const bf16x8*>(As + aRd + mi * 1024 + px0 * 8);
      af[1][mi] = *reinterpret_cast<const bf16x8*>(As + aRd + mi * 1024 + px1 * 8);
    }
    #pragma unroll
    for (int ni = 0; ni < 4; ++ni) {
      bfv[0][ni] = *reinterpret_cast<const bf16x8*>(Bs + bRd + ni * 1024 + px0 * 8);
      bfv[1][ni] = *reinterpret_cast<const bf16x8*>(Bs + bRd + ni * 1024 + px1 * 8);
    }

    {
      const int cs  = c + 2;
      const int ss  = cs % 3;
      const int k0s = (cs < 64 ? cs : 63) * 64;
      STAGE_CHUNK(ss, k0s);
    }

    __builtin_amdgcn_s_setprio(1);
    #pragma unroll
    for (int ks = 0; ks < 2; ++ks)
      #pragma unroll
      for (int mi = 0; mi < 4; ++mi)
        #pragma unroll
        for (int ni = 0; ni < 4; ++ni)
          acc[mi][ni] = __builtin_amdgcn_mfma_f32_16x16x32_bf16(
              af[ks][mi], bfv[ks][ni], acc[mi][ni], 0, 0, 0);
    __builtin_amdgcn_s_setprio(0);

    asm volatile("s_waitcnt vmcnt(6)" ::: "memory");
    __builtin_amdgcn_s_barrier();
    asm volatile("" ::: "memory");
  }
  #undef STAGE_CHUNK

  const int sel = (blockIdx.y >= 8);
  const float* bias = sel ? bs : bp;
  float*  outF = sel ? outS : outP;
  ushort* outB = sel ? Sb : Pb;
  const int colbase = blockIdx.y * 128 - sel * 1024;
  #pragma unroll
  for (int mi = 0; mi < 4; ++mi) {
    #pragma unroll
    for (int ni = 0; ni < 4; ++ni) {
      const int n = colbase + wc * 64 + ni * 16 + r16;
      const float bv = bias[n];
      #pragma unroll
      for (int rg = 0; rg < 4; ++rg) {
        const int m = blockIdx.x * 256 + wr * 64 + mi * 16 + qd * 4 + rg;
        const float v = acc[mi][ni][rg] + bv;
        const size_t off = (size_t)m * 1024 + n;
        outF[off] = v;
        outB[off] = f32_to_bf16_rne(v);
      }
    }
  }
}

// ======================= head: ring-3 BK=64 counted-vmcnt ==================
static __device__ __forceinline__ void load_frags64(
    const ushort* lA, const ushort* lB, bf16x8 af[2][4], bf16x8 bfv[2][4],
    int wr, int wc, int r16, int quad)
{
  #pragma unroll
  for (int ks = 0; ks < 2; ++ks) {
    const int pc = (((ks * 4) + quad) ^ (r16 & 7)) * 8;
    #pragma unroll
    for (int mi = 0; mi < 4; ++mi)
      af[ks][mi] = *reinterpret_cast<const bf16x8*>(lA + (wr * 64 + mi * 16 + r16) * 64 + pc);
    #pragma unroll
    for (int ni = 0; ni < 4; ++ni)
      bfv[ks][ni] = *reinterpret_cast<const bf16x8*>(lB + (wc * 64 + ni * 16 + r16) * 64 + pc);
  }
}

static __device__ __forceinline__ void mfma_frags64(
    bf16x8 af[2][4], bf16x8 bfv[2][4], floatx4 acc[4][4])
{
  __builtin_amdgcn_s_setprio(1);
  #pragma unroll
  for (int ks = 0; ks < 2; ++ks)
    #pragma unroll
    for (int mi = 0; mi < 4; ++mi)
      #pragma unroll
      for (int ni = 0; ni < 4; ++ni)
        acc[mi][ni] = __builtin_amdgcn_mfma_f32_16x16x32_bf16(
            af[ks][mi], bfv[ks][ni], acc[mi][ni], 0, 0, 0);
  __builtin_amdgcn_s_setprio(0);
}

// grid (33, 32): blockIdx.x==32 -> parent logits m-tile blockIdx.y;
// blockIdx.x==c<32 -> child logits for class c, m-tile blockIdx.y.
// Live blocks are contiguous linear ids -> spread across XCDs.
__global__ __launch_bounds__(256) void k_head(
    const ushort* __restrict__ Sb, const ushort* __restrict__ Pb,
    const ushort* __restrict__ cwb, const ushort* __restrict__ Wcb,
    const int* __restrict__ perm, const int* __restrict__ off,
    const float* __restrict__ cb0, const float* __restrict__ cb1,
    const float* __restrict__ bc,
    float* __restrict__ out0, float* __restrict__ out1,
    float* __restrict__ outParent)
{
  __shared__ __align__(16) ushort lA[3 * 128 * 64];   // 48 KB, 3 ring slots
  __shared__ __align__(16) ushort lB[3 * 128 * 64];   // 48 KB, 3 ring slots
  floatx4 acc[4][4];
  const floatx4 z4 = {0.f, 0.f, 0.f, 0.f};
  #pragma unroll
  for (int i = 0; i < 4; ++i)
    #pragma unroll
    for (int j = 0; j < 4; ++j) acc[i][j] = z4;

  const int t = threadIdx.x, w = t >> 6, lane = t & 63;
  const int wr = w >> 1, wc = w & 1, r16 = lane & 15, quad = lane >> 4;
  const int sr = lane >> 3, sc = lane & 7;
  const int gc = sc ^ sr;                 // source 16B-chunk (swizzled)
  const int dRow = 32 * w;                // wave's base row per staging call

  if (blockIdx.x == 32) {                 // ---- parent logits ----
    const ushort* Abase = Pb + (size_t)(blockIdx.y * 128) * 1024;

    #define STAGE_P(slot, k0)                                                  \
      do {                                                                     \
        _Pragma("unroll")                                                      \
        for (int c2 = 0; c2 < 4; ++c2) {                                       \
          const int r = dRow + 8 * c2 + sr;                                    \
          async_copy16(Abase + (size_t)r * 1024 + (k0) + gc * 8,               \
                       lA + (slot) * 8192 + (dRow + 8 * c2) * 64);             \
          async_copy16(Wcb + (size_t)r * 1024 + (k0) + gc * 8,                 \
                       lB + (slot) * 8192 + (dRow + 8 * c2) * 64);             \
        }                                                                      \
      } while (0)

    STAGE_P(0, 0);
    STAGE_P(1, 64);
    asm volatile("s_waitcnt vmcnt(8)" ::: "memory");   // chunk 0's 8 done
    __builtin_amdgcn_s_barrier();
    asm volatile("" ::: "memory");

    for (int c = 0; c < 16; ++c) {
      const int slot = c % 3;
      bf16x8 af[2][4], bfv[2][4];
      load_frags64(lA + slot * 8192, lB + slot * 8192, af, bfv, wr, wc, r16, quad);
      {
        const int cs  = c + 2;
        const int ss  = cs % 3;
        const int k0s = (cs < 16 ? cs : 15) * 64;
        STAGE_P(ss, k0s);
      }
      mfma_frags64(af, bfv, acc);
      asm volatile("s_waitcnt vmcnt(8)" ::: "memory");
      __builtin_amdgcn_s_barrier();
      asm volatile("" ::: "memory");
    }
    #undef STAGE_P

    if (wc == 0) {
      #pragma unroll
      for (int mi = 0; mi < 4; ++mi)
        #pragma unroll
        for (int ni = 0; ni < 2; ++ni) {
          const int n = ni * 16 + r16;
          const float bv = bc[n];
          #pragma unroll
          for (int rg = 0; rg < 4; ++rg) {
            const int m = blockIdx.y * 128 + wr * 64 + mi * 16 + quad * 4 + rg;
            outParent[(size_t)m * 32 + n] = acc[mi][ni][rg] + bv;
          }
        }
    }
    return;
  }

  // ---- child logits for class c ----
  const int cls  = blockIdx.x;
  const int off0 = off[cls];
  const int cnt  = off[cls + 1] - off0;
  const int m0   = blockIdx.y * 128;
  if (m0 >= cnt) return;                        // block-uniform exit

  int rowSamp[4];
  #pragma unroll
  for (int c2 = 0; c2 < 4; ++c2) {
    const int r = dRow + 8 * c2 + sr;
    rowSamp[c2] = perm[off0 + min(m0 + r, cnt - 1)];
  }
  const ushort* Bbase = cwb + (size_t)cls * 128 * 1024;

  #define STAGE_C(slot, k0)                                                    \
    do {                                                                       \
      _Pragma("unroll")                                                        \
      for (int c2 = 0; c2 < 4; ++c2) {                                         \
        const int r = dRow + 8 * c2 + sr;                                      \
        async_copy16(Sb + (size_t)rowSamp[c2] * 1024 + (k0) + gc * 8,          \
                     lA + (slot) * 8192 + (dRow + 8 * c2) * 64);               \
        async_copy16(Bbase + (size_t)r * 1024 + (k0) + gc * 8,                 \
                     lB + (slot) * 8192 + (dRow + 8 * c2) * 64);               \
      }                                                                        \
    } while (0)

  STAGE_C(0, 0);
  STAGE_C(1, 64);
  asm volatile("s_waitcnt vmcnt(8)" ::: "memory");   // chunk 0's 8 done
  __builtin_amdgcn_s_barrier();
  asm volatile("" ::: "memory");

  for (int c = 0; c < 16; ++c) {
    const int slot = c % 3;
    bf16x8 af[2][4], bfv[2][4];
    load_frags64(lA + slot * 8192, lB + slot * 8192, af, bfv, wr, wc, r16, quad);
    {
      const int cs  = c + 2;
      const int ss  = cs % 3;
      const int k0s = (cs < 16 ? cs : 15) * 64;
      STAGE_C(ss, k0s);
    }
    mfma_frags64(af, bfv, acc);
    asm volatile("s_waitcnt vmcnt(8)" ::: "memory");
    __builtin_amdgcn_s_barrier();
    asm volatile("" ::: "memory");
  }
  #undef STAGE_C

  #pragma unroll
  for (int mi = 0; mi < 4; ++mi) {
    #pragma unroll
    for (int rg = 0; rg < 4; ++rg) {
      const int gm = m0 + wr * 64 + mi * 16 + quad * 4 + rg;
      if (gm >= cnt) continue;
      const int sample = perm[off0 + gm];
      #pragma unroll
      for (int ni = 0; ni < 4; ++ni) {
        const int n = wc * 64 + ni * 16 + r16;
        if (n < 32)
          out0[(size_t)sample * 32 + n] = acc[mi][ni][rg] + cb0[cls * 32 + n];
        else if (n < 96)
          out1[(size_t)sample * 64 + (n - 32)] = acc[mi][ni][rg] + cb1[cls * 64 + (n - 32)];
      }
    }
  }
}

// ---------------------------------------------------------------------------

extern "C" void kernel_launch(void* const* d_in, const int* in_sizes, int n_in,
                              void* d_out, int out_size, void* d_ws, size_t ws_size,
                              hipStream_t stream) {
  const float* x   = (const float*)d_in[0];
  const int*   y   = (const int*)  d_in[1];
  const float* Wp  = (const float*)d_in[2];
  const float* bp  = (const float*)d_in[3];
  const float* Ws  = (const float*)d_in[4];
  const float* bs  = (const float*)d_in[5];
  const float* Wc  = (const float*)d_in[6];
  const float* bc  = (const float*)d_in[7];
  const float* cw0 = (const float*)d_in[8];
  const float* cb0 = (const float*)d_in[9];
  const float* cw1 = (const float*)d_in[10];
  const float* cb1 = (const float*)d_in[11];

  float* out = (float*)d_out;
  float* parent_logits = out;               // [4096,32]
  float* child0        = out + 131072;      // [4096,32]
  float* child1        = out + 262144;      // [4096,64]
  float* P             = out + 524288;      // [4096,1024]
  float* S             = out + 4718592;     // [4096,1024]

  char* ws = (char*)d_ws;
  ushort* xb   = (ushort*)(ws);                  // 32 MB   [4096][4096]
  ushort* Bt1  = (ushort*)(ws + 33554432);       // 16 MB   [2048][4096]
  ushort* Pb   = (ushort*)(ws + 50331648);       // 8 MB    [4096][1024]
  ushort* Sb   = (ushort*)(ws + 58720256);       // 8 MB    [4096][1024]
  ushort* cwb  = (ushort*)(ws + 67108864);       // 8 MB    [32][128][1024]
  ushort* Wcb  = (ushort*)(ws + 75497472);       // 256 KB  [128][1024]
  int*    perm = (int*)   (ws + 75759616);       // 16 KB
  int*    offs = (int*)   (ws + 75776000);       // 132 B

  k_prep <<<14465, 256, 0, stream>>>(x, y, Wp, Ws, Wc, cw0, cw1,
                                     xb, Bt1, cwb, Wcb, perm, offs);
  k_gemm1<<<dim3(16, 16), 512, 0, stream>>>(xb, Bt1, bp, bs, P, S, Pb, Sb);
  k_head <<<dim3(33, 32), 256, 0, stream>>>(Sb, Pb, cwb, Wcb, perm, offs,
                                            cb0, cb1, bc,
                                            child0, child1, parent_logits);
}

// Round 4
// 248.234 us; speedup vs baseline: 1.2170x; 1.0172x over previous
//
#include <hip/hip_runtime.h>
#include <hip/hip_bf16.h>
#include <stdint.h>

// ---------------------------------------------------------------------------
// JointEmbeddingClassifier on MI355X (gfx950) — R8.
// R7 post-mortem: head 73.5 -> ~31.5us (grid transpose + ring-3 worked), but
// residual is structural: 1056 blocks at 96KB LDS = 1 block/CU serial
// allocation, 992 of them DEAD (load off[], exit) -> live blocks start
// staggered behind dead-block rounds, run with 4 waves/CU at depth-2 against
// a perm-gathered mostly-L2-miss A stream.
// R8 (k_head only; gemm1/prep-body byte-identical):
//   (1) work-list launch: prep block 0 emits live items {parent m-tiles (32),
//       child (cls,mtile) (<=64)}; k_head = exactly 96 blocks grid-striding
//       the list. No dead-block dispatch serialization.
//   (2) ring-4 depth-3 pipeline: stage chunk c+3 during c, vmcnt(16)
//       (8 loads/chunk/thread) -> ~3 chunks of gather-latency cover.
//       vmcnt carry across items verified (item end leaves <=16 clamped
//       loads; next prologue issues 24, waits vmcnt(16) -> old all drained).
// ---------------------------------------------------------------------------

typedef __attribute__((ext_vector_type(4))) float  floatx4;
typedef __attribute__((ext_vector_type(8))) short  shortx8;
typedef __attribute__((ext_vector_type(4))) short  shortx4;
typedef __attribute__((ext_vector_type(8))) __bf16 bf16x8;

static __device__ __forceinline__ ushort f32_to_bf16_rne(float f) {
  uint32_t u = __builtin_bit_cast(uint32_t, f);
  u += 0x7FFFu + ((u >> 16) & 1u);      // RNE (no NaN inputs here)
  return (ushort)(u >> 16);
}

// async global->LDS, 16B per lane. LDS dest = wave-uniform base + lane*16;
// global address may be fully per-lane (used for perm-indirected rows).
static __device__ __forceinline__ void async_copy16(const void* g, void* lds) {
  __builtin_amdgcn_global_load_lds(
      (__attribute__((address_space(1))) void*)(uintptr_t)g,
      (__attribute__((address_space(3))) void*)(uintptr_t)lds,
      16, 0, 0);
}

// ======================= fused prep (one launch) ===========================
// blocks [0]            : counting sort of y -> perm, offs, work-list
// blocks [1, 4224]      : pack cwb [32][128][1024] + Wcb [128][1024]
// blocks [4225, 6272]   : transpose Wp|Ws -> Bt1 bf16 [2048][4096]
// blocks [6273, 14464]  : cast x f32 -> bf16
__global__ __launch_bounds__(256) void k_prep(
    const float* __restrict__ x,   const int* __restrict__ y,
    const float* __restrict__ Wp,  const float* __restrict__ Ws,
    const float* __restrict__ Wc,
    const float* __restrict__ cw0, const float* __restrict__ cw1,
    ushort* __restrict__ xb,  ushort* __restrict__ Bt1,
    ushort* __restrict__ cwb, ushort* __restrict__ Wcb,
    int* __restrict__ perm, int* __restrict__ offs,
    int* __restrict__ work, int* __restrict__ nwork)
{
  __shared__ __align__(16) ushort tile[64 * 72];
  __shared__ int hist[32], hbase[32], hcur[32];
  const int b = blockIdx.x;
  const int t = threadIdx.x;

  if (b == 0) {
    // ---- bucket: counting sort by class (intra-class order irrelevant) ----
    if (t < 32) { hist[t] = 0; hcur[t] = 0; }
    __syncthreads();
    int yv[16];
    #pragma unroll
    for (int i = 0; i < 16; ++i) { yv[i] = y[t * 16 + i]; atomicAdd(&hist[yv[i]], 1); }
    __syncthreads();
    if (t == 0) {
      int s = 0;
      for (int c = 0; c < 32; ++c) { hbase[c] = s; offs[c] = s; s += hist[c]; }
      offs[32] = s;
      // ---- live-item work list: parent m-tiles then child (cls, mtile) ----
      int nw = 0;
      for (int m = 0; m < 32; ++m) work[nw++] = (32 << 8) | m;
      for (int c = 0; c < 32; ++c)
        for (int m0 = 0; m0 < hist[c]; m0 += 128) work[nw++] = (c << 8) | (m0 >> 7);
      nwork[0] = nw;                     // <= 96
    }
    __syncthreads();
    #pragma unroll
    for (int i = 0; i < 16; ++i) {
      const int c = yv[i];
      const int p = atomicAdd(&hcur[c], 1);
      perm[hbase[c] + p] = t * 16 + i;
    }
  } else if (b <= 4224) {
    // ---- pack cwb (rows: 32 cw0 | 64 cw1 | 32 zero per class) + Wcb ----
    const int row = b - 1;               // 0..4223
    const int k = t * 4;
    float v0 = 0.f, v1 = 0.f, v2 = 0.f, v3 = 0.f;
    ushort* dst;
    if (row < 4096) {
      const int c = row >> 7, n = row & 127;
      if (n < 32) {
        floatx4 f = *reinterpret_cast<const floatx4*>(cw0 + (size_t)(c * 32 + n) * 1024 + k);
        v0 = f[0]; v1 = f[1]; v2 = f[2]; v3 = f[3];
      } else if (n < 96) {
        floatx4 f = *reinterpret_cast<const floatx4*>(cw1 + (size_t)(c * 64 + (n - 32)) * 1024 + k);
        v0 = f[0]; v1 = f[1]; v2 = f[2]; v3 = f[3];
      }
      dst = cwb + (size_t)row * 1024 + k;
    } else {
      const int n = row - 4096;          // 0..127
      if (n < 32) {
        v0 = Wc[(k + 0) * 32 + n]; v1 = Wc[(k + 1) * 32 + n];
        v2 = Wc[(k + 2) * 32 + n]; v3 = Wc[(k + 3) * 32 + n];
      }
      dst = Wcb + (size_t)n * 1024 + k;
    }
    shortx4 o;
    o[0] = (short)f32_to_bf16_rne(v0); o[1] = (short)f32_to_bf16_rne(v1);
    o[2] = (short)f32_to_bf16_rne(v2); o[3] = (short)f32_to_bf16_rne(v3);
    *reinterpret_cast<shortx4*>(dst) = o;
  } else if (b <= 6272) {
    // ---- transpose one 64x64 tile of Wp|Ws into Bt1 (K-contiguous) ----
    const int vt = b - 4225;             // 0..2047
    const int z = vt >> 10, rest = vt & 1023;
    const int nt = rest >> 6, kt = rest & 63;
    const float* W = z ? Ws : Wp;
    const int r = t >> 4, c = (t & 15) * 4;
    #pragma unroll
    for (int j = 0; j < 4; ++j) {
      const int kk = r + j * 16;
      floatx4 v = *reinterpret_cast<const floatx4*>(
          W + (size_t)(kt * 64 + kk) * 1024 + nt * 64 + c);
      tile[(c + 0) * 72 + kk] = f32_to_bf16_rne(v[0]);
      tile[(c + 1) * 72 + kk] = f32_to_bf16_rne(v[1]);
      tile[(c + 2) * 72 + kk] = f32_to_bf16_rne(v[2]);
      tile[(c + 3) * 72 + kk] = f32_to_bf16_rne(v[3]);
    }
    __syncthreads();
    const int nl = t >> 3, ch = t & 7;
    #pragma unroll
    for (int j = 0; j < 2; ++j) {
      const int n = nl + j * 32;
      shortx8 v = *reinterpret_cast<const shortx8*>(tile + n * 72 + ch * 8);
      *reinterpret_cast<shortx8*>(
          Bt1 + (size_t)(z * 1024 + nt * 64 + n) * 4096 + kt * 64 + ch * 8) = v;
    }
  } else {
    // ---- cast x -> bf16 ----
    const size_t i = ((size_t)(b - 6273) * 256 + t) * 8;
    floatx4 a = *reinterpret_cast<const floatx4*>(x + i);
    floatx4 c = *reinterpret_cast<const floatx4*>(x + i + 4);
    shortx8 o;
    o[0] = (short)f32_to_bf16_rne(a[0]); o[1] = (short)f32_to_bf16_rne(a[1]);
    o[2] = (short)f32_to_bf16_rne(a[2]); o[3] = (short)f32_to_bf16_rne(a[3]);
    o[4] = (short)f32_to_bf16_rne(c[0]); o[5] = (short)f32_to_bf16_rne(c[1]);
    o[6] = (short)f32_to_bf16_rne(c[2]); o[7] = (short)f32_to_bf16_rne(c[3]);
    *reinterpret_cast<shortx8*>(xb + i) = o;
  }
}

// ======================= gemm1: 256x128, ring-3 BK=64 counted-vmcnt ========
// (unchanged from R6/R7)
__global__ __launch_bounds__(512, 2) void k_gemm1(
    const ushort* __restrict__ xb, const ushort* __restrict__ Bt1,
    const float* __restrict__ bp, const float* __restrict__ bs,
    float* __restrict__ outP, float* __restrict__ outS,
    ushort* __restrict__ Pb, ushort* __restrict__ Sb)
{
  __shared__ __align__(16) ushort lA[3 * 256 * 64];   // 96 KB, 3 ring slots
  __shared__ __align__(16) ushort lB[3 * 128 * 64];   // 48 KB, 3 ring slots

  floatx4 acc[4][4];
  const floatx4 z4 = {0.f, 0.f, 0.f, 0.f};
  #pragma unroll
  for (int i = 0; i < 4; ++i)
    #pragma unroll
    for (int j = 0; j < 4; ++j) acc[i][j] = z4;

  const int t    = threadIdx.x;
  const int w    = t >> 6;
  const int lane = t & 63;
  const int wr   = w >> 1;      // 0..3 : M wave
  const int wc   = w & 1;       // 0..1 : N wave
  const int r16  = lane & 15;
  const int qd   = lane >> 4;

  const ushort* Abase = xb  + (size_t)(blockIdx.x * 256) * 4096;
  const ushort* Bbase = Bt1 + (size_t)(blockIdx.y * 128) * 4096;

  const int    rS   = t >> 3;                               // 0..63 row-in-call
  const int    qs   = ((t & 7) ^ (rS & 7)) << 3;            // elem offset
  const int    dUni = (t & ~63) * 8;   // wave-uniform dest base (ushorts)

  const int px0 = (0 * 4 + qd) ^ (r16 & 7);
  const int px1 = (1 * 4 + qd) ^ (r16 & 7);
  const int aRd = (wr * 64 + r16) * 64;
  const int bRd = (wc * 64 + r16) * 64;

  #define STAGE_CHUNK(slot, k0)                                                \
    do {                                                                       \
      _Pragma("unroll")                                                        \
      for (int j = 0; j < 4; ++j)                                              \
        async_copy16(Abase + (size_t)(j * 64 + rS) * 4096 + (k0) + qs,         \
                     lA + (slot) * 16384 + j * 4096 + dUni);                   \
      _Pragma("unroll")                                                        \
      for (int j = 0; j < 2; ++j)                                              \
        async_copy16(Bbase + (size_t)(j * 64 + rS) * 4096 + (k0) + qs,         \
                     lB + (slot) * 8192 + j * 4096 + dUni);                    \
    } while (0)

  STAGE_CHUNK(0, 0);
  STAGE_CHUNK(1, 64);
  asm volatile("s_waitcnt vmcnt(6)" ::: "memory");   // chunk 0's 6 done
  __builtin_amdgcn_s_barrier();
  asm volatile("" ::: "memory");

  for (int c = 0; c < 64; ++c) {
    const int slot = c % 3;
    const ushort* As = lA + slot * 16384;
    const ushort* Bs = lB + slot * 8192;

    bf16x8 af[2][4], bfv[2][4];
    #pragma unroll
    for (int mi = 0; mi < 4; ++mi) {
      af[0][mi] = *reinterpret_cast<const bf16x8*>(As + aRd + mi * 1024 + px0 * 8);
      af[1][mi] = *reinterpret_cast<const bf16x8*>(As + aRd + mi * 1024 + px1 * 8);
    }
    #pragma unroll
    for (int ni = 0; ni < 4; ++ni) {
      bfv[0][ni] = *reinterpret_cast<const bf16x8*>(Bs + bRd + ni * 1024 + px0 * 8);
      bfv[1][ni] = *reinterpret_cast<const bf16x8*>(Bs + bRd + ni * 1024 + px1 * 8);
    }

    {
      const int cs  = c + 2;
      const int ss  = cs % 3;
      const int k0s = (cs < 64 ? cs : 63) * 64;
      STAGE_CHUNK(ss, k0s);
    }

    __builtin_amdgcn_s_setprio(1);
    #pragma unroll
    for (int ks = 0; ks < 2; ++ks)
      #pragma unroll
      for (int mi = 0; mi < 4; ++mi)
        #pragma unroll
        for (int ni = 0; ni < 4; ++ni)
          acc[mi][ni] = __builtin_amdgcn_mfma_f32_16x16x32_bf16(
              af[ks][mi], bfv[ks][ni], acc[mi][ni], 0, 0, 0);
    __builtin_amdgcn_s_setprio(0);

    asm volatile("s_waitcnt vmcnt(6)" ::: "memory");
    __builtin_amdgcn_s_barrier();
    asm volatile("" ::: "memory");
  }
  #undef STAGE_CHUNK

  const int sel = (blockIdx.y >= 8);
  const float* bias = sel ? bs : bp;
  float*  outF = sel ? outS : outP;
  ushort* outB = sel ? Sb : Pb;
  const int colbase = blockIdx.y * 128 - sel * 1024;
  #pragma unroll
  for (int mi = 0; mi < 4; ++mi) {
    #pragma unroll
    for (int ni = 0; ni < 4; ++ni) {
      const int n = colbase + wc * 64 + ni * 16 + r16;
      const float bv = bias[n];
      #pragma unroll
      for (int rg = 0; rg < 4; ++rg) {
        const int m = blockIdx.x * 256 + wr * 64 + mi * 16 + qd * 4 + rg;
        const float v = acc[mi][ni][rg] + bv;
        const size_t off = (size_t)m * 1024 + n;
        outF[off] = v;
        outB[off] = f32_to_bf16_rne(v);
      }
    }
  }
}

// ======================= head: work-list, ring-4 depth-3 ===================
static __device__ __forceinline__ void load_frags64(
    const ushort* lA, const ushort* lB, bf16x8 af[2][4], bf16x8 bfv[2][4],
    int wr, int wc, int r16, int quad)
{
  #pragma unroll
  for (int ks = 0; ks < 2; ++ks) {
    const int pc = (((ks * 4) + quad) ^ (r16 & 7)) * 8;
    #pragma unroll
    for (int mi = 0; mi < 4; ++mi)
      af[ks][mi] = *reinterpret_cast<const bf16x8*>(lA + (wr * 64 + mi * 16 + r16) * 64 + pc);
    #pragma unroll
    for (int ni = 0; ni < 4; ++ni)
      bfv[ks][ni] = *reinterpret_cast<const bf16x8*>(lB + (wc * 64 + ni * 16 + r16) * 64 + pc);
  }
}

static __device__ __forceinline__ void mfma_frags64(
    bf16x8 af[2][4], bf16x8 bfv[2][4], floatx4 acc[4][4])
{
  __builtin_amdgcn_s_setprio(1);
  #pragma unroll
  for (int ks = 0; ks < 2; ++ks)
    #pragma unroll
    for (int mi = 0; mi < 4; ++mi)
      #pragma unroll
      for (int ni = 0; ni < 4; ++ni)
        acc[mi][ni] = __builtin_amdgcn_mfma_f32_16x16x32_bf16(
            af[ks][mi], bfv[ks][ni], acc[mi][ni], 0, 0, 0);
  __builtin_amdgcn_s_setprio(0);
}

// 96 blocks grid-stride the live-item list. item = (cls<<8)|mtile;
// cls==32 -> parent logits m-tile; cls<32 -> child logits for class cls.
__global__ __launch_bounds__(256) void k_head(
    const ushort* __restrict__ Sb, const ushort* __restrict__ Pb,
    const ushort* __restrict__ cwb, const ushort* __restrict__ Wcb,
    const int* __restrict__ perm, const int* __restrict__ off,
    const int* __restrict__ work, const int* __restrict__ nwork,
    const float* __restrict__ cb0, const float* __restrict__ cb1,
    const float* __restrict__ bc,
    float* __restrict__ out0, float* __restrict__ out1,
    float* __restrict__ outParent)
{
  __shared__ __align__(16) ushort lA[4 * 128 * 64];   // 64 KB, 4 ring slots
  __shared__ __align__(16) ushort lB[4 * 128 * 64];   // 64 KB, 4 ring slots

  const int t = threadIdx.x, w = t >> 6, lane = t & 63;
  const int wr = w >> 1, wc = w & 1, r16 = lane & 15, quad = lane >> 4;
  const int sr = lane >> 3, sc = lane & 7;
  const int gc = sc ^ sr;                 // source 16B-chunk (swizzled)
  const int dRow = 32 * w;                // wave's base row per staging call
  const int nW = nwork[0];

  for (int wi = blockIdx.x; wi < nW; wi += 96) {
    const int item = work[wi];
    const int cls  = item >> 8;           // 0..32
    const int mt   = item & 255;          // m-tile index

    floatx4 acc[4][4];
    const floatx4 z4 = {0.f, 0.f, 0.f, 0.f};
    #pragma unroll
    for (int i = 0; i < 4; ++i)
      #pragma unroll
      for (int j = 0; j < 4; ++j) acc[i][j] = z4;

    // per-item A/B addressing
    int off0 = 0, cnt = 0;
    const ushort* Asrc;
    const ushort* Bb;
    int rowG[4];
    if (cls == 32) {                      // parent: A = Pb rows, B = Wcb
      Asrc = Pb;
      Bb   = Wcb;
      #pragma unroll
      for (int c2 = 0; c2 < 4; ++c2) rowG[c2] = mt * 128 + dRow + 8 * c2 + sr;
    } else {                              // child: A = Sb rows via perm
      off0 = off[cls];
      cnt  = off[cls + 1] - off0;
      Asrc = Sb;
      Bb   = cwb + (size_t)cls * 128 * 1024;
      #pragma unroll
      for (int c2 = 0; c2 < 4; ++c2) {
        const int r = mt * 128 + dRow + 8 * c2 + sr;
        rowG[c2] = perm[off0 + min(r, cnt - 1)];
      }
    }

    #define STAGE_H(slot, k0)                                                  \
      do {                                                                     \
        _Pragma("unroll")                                                      \
        for (int c2 = 0; c2 < 4; ++c2) {                                       \
          async_copy16(Asrc + (size_t)rowG[c2] * 1024 + (k0) + gc * 8,         \
                       lA + (slot) * 8192 + (dRow + 8 * c2) * 64);             \
          async_copy16(Bb + (size_t)(dRow + 8 * c2 + sr) * 1024 + (k0) + gc * 8,\
                       lB + (slot) * 8192 + (dRow + 8 * c2) * 64);             \
        }                                                                      \
      } while (0)

    // prologue: stage chunks 0,1,2 (24 loads); vmcnt(16) -> chunk 0's 8 done
    // (also drains any clamped leftovers from the previous item: <=16 old +
    //  24 new - 16 kept = old fully complete + new chunk 0).
    STAGE_H(0, 0);
    STAGE_H(1, 64);
    STAGE_H(2, 128);
    asm volatile("s_waitcnt vmcnt(16)" ::: "memory");
    __builtin_amdgcn_s_barrier();
    asm volatile("" ::: "memory");

    for (int c = 0; c < 16; ++c) {
      const int slot = c & 3;
      bf16x8 af[2][4], bfv[2][4];
      load_frags64(lA + slot * 8192, lB + slot * 8192, af, bfv, wr, wc, r16, quad);
      {
        const int cs  = c + 3;            // depth-3 prefetch
        const int ss  = cs & 3;
        const int k0s = (cs < 16 ? cs : 15) * 64;
        STAGE_H(ss, k0s);
      }
      mfma_frags64(af, bfv, acc);
      // <=16 outstanding leaves chunks {c+2,c+3} in flight -> c+1 resident.
      asm volatile("s_waitcnt vmcnt(16)" ::: "memory");
      __builtin_amdgcn_s_barrier();
      asm volatile("" ::: "memory");
    }
    #undef STAGE_H

    // epilogue
    if (cls == 32) {
      if (wc == 0) {
        #pragma unroll
        for (int mi = 0; mi < 4; ++mi)
          #pragma unroll
          for (int ni = 0; ni < 2; ++ni) {
            const int n = ni * 16 + r16;
            const float bv = bc[n];
            #pragma unroll
            for (int rg = 0; rg < 4; ++rg) {
              const int m = mt * 128 + wr * 64 + mi * 16 + quad * 4 + rg;
              outParent[(size_t)m * 32 + n] = acc[mi][ni][rg] + bv;
            }
          }
      }
    } else {
      const int m0 = mt * 128;
      #pragma unroll
      for (int mi = 0; mi < 4; ++mi) {
        #pragma unroll
        for (int rg = 0; rg < 4; ++rg) {
          const int gm = m0 + wr * 64 + mi * 16 + quad * 4 + rg;
          if (gm >= cnt) continue;
          const int sample = perm[off0 + gm];
          #pragma unroll
          for (int ni = 0; ni < 4; ++ni) {
            const int n = wc * 64 + ni * 16 + r16;
            if (n < 32)
              out0[(size_t)sample * 32 + n] = acc[mi][ni][rg] + cb0[cls * 32 + n];
            else if (n < 96)
              out1[(size_t)sample * 64 + (n - 32)] = acc[mi][ni][rg] + cb1[cls * 64 + (n - 32)];
          }
        }
      }
    }
  }
}

// ---------------------------------------------------------------------------

extern "C" void kernel_launch(void* const* d_in, const int* in_sizes, int n_in,
                              void* d_out, int out_size, void* d_ws, size_t ws_size,
                              hipStream_t stream) {
  const float* x   = (const float*)d_in[0];
  const int*   y   = (const int*)  d_in[1];
  const float* Wp  = (const float*)d_in[2];
  const float* bp  = (const float*)d_in[3];
  const float* Ws  = (const float*)d_in[4];
  const float* bs  = (const float*)d_in[5];
  const float* Wc  = (const float*)d_in[6];
  const float* bc  = (const float*)d_in[7];
  const float* cw0 = (const float*)d_in[8];
  const float* cb0 = (const float*)d_in[9];
  const float* cw1 = (const float*)d_in[10];
  const float* cb1 = (const float*)d_in[11];

  float* out = (float*)d_out;
  float* parent_logits = out;               // [4096,32]
  float* child0        = out + 131072;      // [4096,32]
  float* child1        = out + 262144;      // [4096,64]
  float* P             = out + 524288;      // [4096,1024]
  float* S             = out + 4718592;     // [4096,1024]

  char* ws = (char*)d_ws;
  ushort* xb   = (ushort*)(ws);                  // 32 MB   [4096][4096]
  ushort* Bt1  = (ushort*)(ws + 33554432);       // 16 MB   [2048][4096]
  ushort* Pb   = (ushort*)(ws + 50331648);       // 8 MB    [4096][1024]
  ushort* Sb   = (ushort*)(ws + 58720256);       // 8 MB    [4096][1024]
  ushort* cwb  = (ushort*)(ws + 67108864);       // 8 MB    [32][128][1024]
  ushort* Wcb  = (ushort*)(ws + 75497472);       // 256 KB  [128][1024]
  int*    perm = (int*)   (ws + 75759616);       // 16 KB
  int*    offs = (int*)   (ws + 75776000);       // 132 B
  int*    work = (int*)   (ws + 75776256);       // 512 B  (<=96 items)
  int*    nwk  = (int*)   (ws + 75776768);       // 4 B

  k_prep <<<14465, 256, 0, stream>>>(x, y, Wp, Ws, Wc, cw0, cw1,
                                     xb, Bt1, cwb, Wcb, perm, offs, work, nwk);
  k_gemm1<<<dim3(16, 16), 512, 0, stream>>>(xb, Bt1, bp, bs, P, S, Pb, Sb);
  k_head <<<96, 256, 0, stream>>>(Sb, Pb, cwb, Wcb, perm, offs, work, nwk,
                                  cb0, cb1, bc,
                                  child0, child1, parent_logits);
}